// Round 12
// baseline (311.264 us; speedup 1.0000x reference)
//
#include <hip/hip_runtime.h>
#include <math.h>

#define HIDDEN 2048
#define NHEADS 32
#define HDIM 64
#define GNUM 8
#define KVDIM 512
#define BB 2
#define SS 2048
#define MROWS (BB * SS)   // 4096
#define NQKV 3072

typedef _Float16 half8 __attribute__((ext_vector_type(8)));
typedef _Float16 half4 __attribute__((ext_vector_type(4)));
typedef _Float16 half2 __attribute__((ext_vector_type(2)));
typedef __fp16 fp16x2 __attribute__((ext_vector_type(2)));
typedef float floatx4 __attribute__((ext_vector_type(4)));

#define MFMA16(a, b, c) __builtin_amdgcn_mfma_f32_16x16x32_f16((a), (b), (c), 0, 0, 0)

// split x = hi + (lo/32), lo scaled by 32 (fp16-normal; /32 on consumers is exact)
__device__ __forceinline__ void split_f32(float x, _Float16& hi, _Float16& lo) {
    hi = (_Float16)x;
    lo = (_Float16)((x - (float)hi) * 32.0f);
}

__device__ __forceinline__ void load_lds16(const void* g, void* l) {
    __builtin_amdgcn_global_load_lds(
        (const __attribute__((address_space(1))) void*)g,
        (__attribute__((address_space(3))) void*)l, 16, 0, 0);
}

// permlane swaps (gfx950): exchange 32-lane halves / odd-even 16-rows of two VGPRs
__device__ __forceinline__ void permswap32(unsigned& a, unsigned& b) {
    asm volatile("v_permlane32_swap_b32 %0, %1" : "+v"(a), "+v"(b));
}
__device__ __forceinline__ void permswap16(unsigned& a, unsigned& b) {
    asm volatile("v_permlane16_swap_b32 %0, %1" : "+v"(a), "+v"(b));
}

__device__ __forceinline__ unsigned pk_f16(float a, float b) {
    union { fp16x2 h; unsigned u; } c;
    c.h = __builtin_amdgcn_cvt_pkrtz(a, b);
    return c.u;
}

// ---------------------------------------------------------------------------
// x [4096][2048] f32 -> xh, xl fp16 (xl = lo*32)
// ---------------------------------------------------------------------------
__global__ __launch_bounds__(256)
void split_x(const float* __restrict__ x, _Float16* __restrict__ xh,
             _Float16* __restrict__ xl, int n4) {
    for (int idx = blockIdx.x * 256 + threadIdx.x; idx < n4; idx += gridDim.x * 256) {
        floatx4 v = reinterpret_cast<const floatx4*>(x)[idx];
        half4 h, l;
        #pragma unroll
        for (int e = 0; e < 4; ++e) { _Float16 hi, lo; split_f32(v[e], hi, lo); h[e] = hi; l[e] = lo; }
        reinterpret_cast<half4*>(xh)[idx] = h;
        reinterpret_cast<half4*>(xl)[idx] = l;
    }
}

// ---------------------------------------------------------------------------
// W [2048][N] f32 -> Wt rows [n0 .. n0+N) of [NQKV][2048] fp16 hi/lo (transposed)
// ---------------------------------------------------------------------------
__global__ __launch_bounds__(256)
void split_wt(const float* __restrict__ W, int N, int n0,
              _Float16* __restrict__ Wth, _Float16* __restrict__ Wtl) {
    __shared__ float tile[64][68];
    const int tid = threadIdx.x;
    const int kb = blockIdx.x, nb = blockIdx.y;
    #pragma unroll
    for (int i = 0; i < 4; ++i) {
        int idx = tid + i * 256;           // 64 rows x 16 float4
        int r = idx >> 4, c4 = idx & 15;
        floatx4 v = *reinterpret_cast<const floatx4*>(&W[(size_t)(kb * 64 + r) * N + nb * 64 + c4 * 4]);
        *reinterpret_cast<floatx4*>(&tile[r][c4 * 4]) = v;
    }
    __syncthreads();
    #pragma unroll
    for (int i = 0; i < 4; ++i) {
        int idx = tid + i * 256;
        int r2 = idx >> 4, c2 = (idx & 15) * 4;   // r2 = local n, c2 = local k
        half4 h, l;
        #pragma unroll
        for (int e = 0; e < 4; ++e) {
            _Float16 hi, lo;
            split_f32(tile[c2 + e][r2], hi, lo);
            h[e] = hi; l[e] = lo;
        }
        size_t o = (size_t)(n0 + nb * 64 + r2) * HIDDEN + kb * 64 + c2;
        *reinterpret_cast<half4*>(&Wth[o]) = h;
        *reinterpret_cast<half4*>(&Wtl[o]) = l;
    }
}

__global__ __launch_bounds__(256)
void biascat_k(const float* __restrict__ bq, const float* __restrict__ bk,
               const float* __restrict__ bv, float* __restrict__ bias) {
    int i = blockIdx.x * 256 + threadIdx.x;
    if (i < 2048) bias[i] = bq[i];
    else if (i < 2560) bias[i] = bk[i - 2048];
    else if (i < NQKV) bias[i] = bv[i - 2560];
}

// ---------------------------------------------------------------------------
// Unified QKV GEMM, SINGLE-ACCUMULATOR split-fp16:
//   acc += ah*bh + (ah/32)*(bl*32) + (al*32)*(bh/32)   (all at true scale;
//   /32 and *32 are exact fp16 exponent shifts).
// 128x128 tile, BK=32 single-buffer (32 KB LDS) -> 3 blocks/CU (m97 regime).
// K tiles [s][dim], V tiles [dim][s] written pre-swizzled for attn DMA.
// V-only column blocks (bn>=20) use 1-term hi*hi (V stored fp16 anyway).
// ---------------------------------------------------------------------------
__global__ __launch_bounds__(256, 2)
void gemm_qkv(const _Float16* __restrict__ xh, const _Float16* __restrict__ xl,
              const _Float16* __restrict__ Wth, const _Float16* __restrict__ Wtl,
              const float* __restrict__ bias,
              _Float16* __restrict__ qh, _Float16* __restrict__ ql,
              _Float16* __restrict__ khs, _Float16* __restrict__ kls,
              _Float16* __restrict__ vhs) {
    __shared__ __align__(16) _Float16 Ah[128 * 32];   // 8 KB each, single buffer
    __shared__ __align__(16) _Float16 Al[128 * 32];
    __shared__ __align__(16) _Float16 Bh[128 * 32];
    __shared__ __align__(16) _Float16 Bl[128 * 32];

    const int tid  = threadIdx.x;
    const int lane = tid & 63;
    const int w    = tid >> 6;
    const int wm   = w >> 1, wn = w & 1;
    const int bm   = blockIdx.x, bn = blockIdx.y;
    const int ml   = lane & 15;
    const int kg8  = (lane >> 4) * 8;
    const bool lo3 = (bn < 20);   // Q/K blocks 3-term; V blocks (cols>=2560) 1-term

    const _Float16* gsrc;
    _Float16* ldst;
    if      (w == 0) { gsrc = xh  + (size_t)(bm * 128) * HIDDEN; ldst = Ah; }
    else if (w == 1) { gsrc = xl  + (size_t)(bm * 128) * HIDDEN; ldst = Al; }
    else if (w == 2) { gsrc = Wth + (size_t)(bn * 128) * HIDDEN; ldst = Bh; }
    else             { gsrc = Wtl + (size_t)(bn * 128) * HIDDEN; ldst = Bl; }
    const bool do_stage = lo3 || (w == 0) || (w == 2);

    floatx4 acc[4][4] = {};
    const _Float16 inv32 = (_Float16)0.03125f;

    for (int t = 0; t < HIDDEN / 32; ++t) {
        __syncthreads();                     // previous tile fully consumed
        if (do_stage) {
            const int k0 = t * 32;
            #pragma unroll
            for (int i = 0; i < 8; ++i) {
                int L   = i * 1024 + lane * 16;            // linear LDS byte in 8 KB
                int row = L >> 6;                          // 64 B rows
                int off = (L & 63) ^ (((row >> 1) & 3) << 4);
                load_lds16((const char*)(gsrc + (size_t)row * HIDDEN + k0) + off,
                           ldst + i * 512);
            }
        }
        __syncthreads();                     // stage visible (implicit vmcnt drain)

        if (lo3) {
            half8 b_h[4], b_l[4], bh32[4];
            #pragma unroll
            for (int c = 0; c < 4; ++c) {
                int row = wn * 64 + c * 16 + ml;
                int byt = row * 64 + ((kg8 * 2) ^ (((row >> 1) & 3) << 4));
                b_h[c] = *reinterpret_cast<const half8*>((const char*)Bh + byt);
                b_l[c] = *reinterpret_cast<const half8*>((const char*)Bl + byt);
                bh32[c] = b_h[c] * inv32;
            }
            #pragma unroll
            for (int r = 0; r < 4; ++r) {
                int row = wm * 64 + r * 16 + ml;
                int byt = row * 64 + ((kg8 * 2) ^ (((row >> 1) & 3) << 4));
                half8 a_h = *reinterpret_cast<const half8*>((const char*)Ah + byt);
                half8 a_l = *reinterpret_cast<const half8*>((const char*)Al + byt);
                half8 ah32 = a_h * inv32;
                #pragma unroll
                for (int c = 0; c < 4; ++c) {
                    acc[r][c] = MFMA16(a_h,  b_h[c],  acc[r][c]);
                    acc[r][c] = MFMA16(ah32, b_l[c],  acc[r][c]);
                    acc[r][c] = MFMA16(a_l,  bh32[c], acc[r][c]);
                }
            }
        } else {
            half8 b_h[4];
            #pragma unroll
            for (int c = 0; c < 4; ++c) {
                int row = wn * 64 + c * 16 + ml;
                int byt = row * 64 + ((kg8 * 2) ^ (((row >> 1) & 3) << 4));
                b_h[c] = *reinterpret_cast<const half8*>((const char*)Bh + byt);
            }
            #pragma unroll
            for (int r = 0; r < 4; ++r) {
                int row = wm * 64 + r * 16 + ml;
                int byt = row * 64 + ((kg8 * 2) ^ (((row >> 1) & 3) << 4));
                half8 a_h = *reinterpret_cast<const half8*>((const char*)Ah + byt);
                #pragma unroll
                for (int c = 0; c < 4; ++c)
                    acc[r][c] = MFMA16(a_h, b_h[c], acc[r][c]);
            }
        }
    }

    // epilogue
    #pragma unroll
    for (int c = 0; c < 4; ++c) {
        int colg = bn * 128 + wn * 64 + c * 16 + ml;
        float bval = bias[colg];
        #pragma unroll
        for (int r = 0; r < 4; ++r) {
            int rowg = bm * 128 + wm * 64 + r * 16 + (lane >> 4) * 4;
            #pragma unroll
            for (int reg = 0; reg < 4; ++reg) {
                float val = acc[r][c][reg] + bval;
                int rr = rowg + reg;
                if (colg < 2048) {
                    _Float16 hi, lo; split_f32(val, hi, lo);
                    qh[(size_t)rr * HIDDEN + colg] = hi;
                    ql[(size_t)rr * HIDDEN + colg] = lo;
                } else if (colg < 2560) {
                    // K: tiled [bg][kt][s(64)][d(64)], col d swizzled by s&7
                    int ck = colg - 2048;
                    int gk = ck >> 6, dk = ck & 63;
                    int bk_ = rr >> 11, sk_ = rr & 2047;
                    int kk = sk_ & 63;
                    size_t baseK = ((size_t)((bk_ * 8 + gk) * 32 + (sk_ >> 6))) * 4096
                                 + kk * 64 + (dk ^ ((kk & 7) << 3));
                    _Float16 hi, lo; split_f32(val, hi, lo);
                    khs[baseK] = hi;
                    kls[baseK] = lo;
                } else {
                    // V: tiled TRANSPOSED [bg][kt][d(64)][s(64)], col s swizzled by d&7
                    int ck = colg - 2560;
                    int gk = ck >> 6, dk = ck & 63;
                    int bk_ = rr >> 11, sk_ = rr & 2047;
                    int s6 = sk_ & 63;
                    size_t baseV = ((size_t)((bk_ * 8 + gk) * 32 + (sk_ >> 6))) * 4096
                                 + dk * 64 + (s6 ^ ((dk & 7) << 3));
                    vhs[baseV] = (_Float16)val;
                }
            }
        }
    }
}

// ---------------------------------------------------------------------------
// Fused attention (R10-proven attn7), in-register scores; K AND V staged via
// global_load_lds DMA from pre-swizzled tiled layouts (w0:K_hi w1:K_lo w2:V^T).
//   S^T = mfma(K,Q); floor/mask in regs; permlane32+16 swap -> SV B-frags;
//   out^T = mfma(V^T, S^T).  Block = (b, g, 64 q-rows), 4 heads share K/V.
// ---------------------------------------------------------------------------
__global__ __launch_bounds__(256, 2)
void attn7(const _Float16* __restrict__ qh, const _Float16* __restrict__ ql,
           const _Float16* __restrict__ khs, const _Float16* __restrict__ kls,
           const _Float16* __restrict__ vhs, const int* __restrict__ mask,
           float* __restrict__ out) {
    __shared__ __align__(16) _Float16 Ksh[64 * 64];   // linear, XOR-swizzled content
    __shared__ __align__(16) _Float16 Ksl[64 * 64];
    __shared__ __align__(16) _Float16 Vs[64 * 64];    // [dim][s], swizzled content

    const int tid  = threadIdx.x;
    const int lane = tid & 63;
    const int w    = tid >> 6;
    const int ml   = lane & 15;
    const int lg   = lane >> 4;
    const int kg8  = lg * 8;

    // XCD-aware remap: all 32 q-tiles of one (b,g) on the same XCD
    const int f_  = blockIdx.y * 32 + blockIdx.x;      // 0..511
    const int bg  = (f_ & 7) | ((f_ >> 8) << 3);
    const int qt  = (f_ >> 3) & 31;
    const int b   = bg >> 3, g = bg & 7;

    // hoist Q fragments (16 rows this wave, 4 heads), pre-scaled by 1/8 (exact)
    half8 qhf[4][2], qlf[4][2];
    {
        size_t rowbase = (size_t)(b * SS + qt * 64 + w * 16 + ml) * HIDDEN;
        #pragma unroll
        for (int hh = 0; hh < 4; ++hh) {
            int hcol = (g * 4 + hh) * HDIM;
            #pragma unroll
            for (int gch = 0; gch < 2; ++gch) {
                half8 a = *reinterpret_cast<const half8*>(&qh[rowbase + hcol + gch * 32 + kg8]);
                half8 c = *reinterpret_cast<const half8*>(&ql[rowbase + hcol + gch * 32 + kg8]);
                qhf[hh][gch] = a * (_Float16)0.125f;
                qlf[hh][gch] = c * (_Float16)0.125f;
            }
        }
    }

    const _Float16* ktile_h = khs + (size_t)(bg * 32) * 4096;
    const _Float16* ktile_l = kls + (size_t)(bg * 32) * 4096;
    const _Float16* vtile   = vhs + (size_t)(bg * 32) * 4096;
    const int* mb = mask + b * SS;

    floatx4 oacc[4][4] = {};   // [head][dim-frag]; col=q, row=d

    for (int kt = 0; kt < SS / 64; ++kt) {
        __syncthreads();   // previous tile fully consumed
        if (w == 0) {
            #pragma unroll
            for (int j = 0; j < 8; ++j)
                load_lds16((const char*)(ktile_h + (size_t)kt * 4096) + j * 1024 + lane * 16,
                           (char*)Ksh + j * 1024);
        } else if (w == 1) {
            #pragma unroll
            for (int j = 0; j < 8; ++j)
                load_lds16((const char*)(ktile_l + (size_t)kt * 4096) + j * 1024 + lane * 16,
                           (char*)Ksl + j * 1024);
        } else if (w == 2) {
            #pragma unroll
            for (int j = 0; j < 8; ++j)
                load_lds16((const char*)(vtile + (size_t)kt * 4096) + j * 1024 + lane * 16,
                           (char*)Vs + j * 1024);
        }
        __syncthreads();

        // hoist V^T fragments (shared across heads); same swizzled pattern as K
        half8 av[4][2];
        #pragma unroll
        for (int f = 0; f < 4; ++f) {
            int vrow = f * 16 + ml;
            int vxo = (vrow & 7) << 3;
            #pragma unroll
            for (int kc = 0; kc < 2; ++kc)
                av[f][kc] = *reinterpret_cast<const half8*>(
                    &Vs[vrow * 64 + ((kc * 32 + kg8) ^ vxo)]);
        }

        int4 m4v[4];
        #pragma unroll
        for (int fc = 0; fc < 4; ++fc)
            m4v[fc] = *reinterpret_cast<const int4*>(&mb[kt * 64 + fc * 16 + lg * 4]);

        __builtin_amdgcn_s_setprio(1);

        // QK^T (swapped): per fc read K-frags once, all 4 heads consume
        unsigned h2[4][4][2];   // [hh][fc][p] packed fp16 score pairs
        #pragma unroll
        for (int fc = 0; fc < 4; ++fc) {
            int krow = fc * 16 + ml;
            int xo = (krow & 7) << 3;
            half8 k_h[2], k_l[2];
            #pragma unroll
            for (int gch = 0; gch < 2; ++gch) {
                k_h[gch] = *reinterpret_cast<const half8*>(&Ksh[krow * 64 + ((gch * 32 + kg8) ^ xo)]);
                k_l[gch] = *reinterpret_cast<const half8*>(&Ksl[krow * 64 + ((gch * 32 + kg8) ^ xo)]);
            }
            #pragma unroll
            for (int hh = 0; hh < 4; ++hh) {
                floatx4 s0 = {}, sl = {};
                s0 = MFMA16(k_h[0], qhf[hh][0], s0);
                s0 = MFMA16(k_h[1], qhf[hh][1], s0);
                sl = MFMA16(k_l[0], qhf[hh][0], sl);
                sl = MFMA16(k_l[1], qhf[hh][1], sl);
                sl = MFMA16(k_h[0], qlf[hh][0], sl);
                sl = MFMA16(k_h[1], qlf[hh][1], sl);
                float sv[4];
                #pragma unroll
                for (int r = 0; r < 4; ++r) {
                    float t = floorf(fmaf(sl[r], 1.0f / 32.0f, s0[r]));
                    sv[r] = (m4v[fc][r] == 0) ? -INFINITY : t;
                }
                h2[hh][fc][0] = pk_f16(sv[0], sv[1]);
                h2[hh][fc][1] = pk_f16(sv[2], sv[3]);
            }
        }

        // S @ V via out^T = mfma(V^T-frag, S^T-B-frag built by permlane swaps)
        #pragma unroll
        for (int hh = 0; hh < 4; ++hh) {
            #pragma unroll
            for (int kc = 0; kc < 2; ++kc) {
                unsigned t0 = h2[hh][2 * kc][0], tA = h2[hh][2 * kc + 1][0];
                unsigned t1 = h2[hh][2 * kc][1], tB = h2[hh][2 * kc + 1][1];
                permswap32(t0, tA); permswap16(t0, tA);
                permswap32(t1, tB); permswap16(t1, tB);
                union { unsigned u[4]; half8 h; } bu;
                bu.u[0] = t0; bu.u[1] = t1; bu.u[2] = tA; bu.u[3] = tB;
                #pragma unroll
                for (int f = 0; f < 4; ++f)
                    oacc[hh][f] = MFMA16(av[f][kc], bu.h, oacc[hh][f]);
            }
        }
        __builtin_amdgcn_s_setprio(0);
    }

    // epilogue: out^T layout -> float4 stores (4 consecutive dims per store)
    #pragma unroll
    for (int hh = 0; hh < 4; ++hh) {
        int hcol = (g * 4 + hh) * HDIM;
        #pragma unroll
        for (int f = 0; f < 4; ++f) {
            size_t row = (size_t)(b * SS + qt * 64 + w * 16 + ml);
            *reinterpret_cast<floatx4*>(&out[row * HIDDEN + hcol + f * 16 + lg * 4]) = oacc[hh][f];
        }
    }
}

extern "C" void kernel_launch(void* const* d_in, const int* in_sizes, int n_in,
                              void* d_out, int out_size, void* d_ws, size_t ws_size,
                              hipStream_t stream) {
    (void)in_sizes; (void)n_in; (void)out_size; (void)ws_size;
    const float* x    = (const float*)d_in[0];
    const int*   mask = (const int*)d_in[1];
    const float* Wq   = (const float*)d_in[2];
    const float* bq   = (const float*)d_in[3];
    const float* Wk   = (const float*)d_in[4];
    const float* bk   = (const float*)d_in[5];
    const float* Wv   = (const float*)d_in[6];
    const float* bv   = (const float*)d_in[7];

    _Float16* ws16 = (_Float16*)d_ws;
    size_t o = 0;
    auto alloc16 = [&](size_t n) { _Float16* p = ws16 + o; o += n; return p; };
    _Float16* xh  = alloc16((size_t)MROWS * HIDDEN);
    _Float16* xl  = alloc16((size_t)MROWS * HIDDEN);
    _Float16* Wth = alloc16((size_t)NQKV * HIDDEN);
    _Float16* Wtl = alloc16((size_t)NQKV * HIDDEN);
    _Float16* qh  = alloc16((size_t)MROWS * HIDDEN);
    _Float16* ql  = alloc16((size_t)MROWS * HIDDEN);
    _Float16* khs = alloc16((size_t)MROWS * KVDIM);
    _Float16* kls = alloc16((size_t)MROWS * KVDIM);
    _Float16* vhs = alloc16((size_t)MROWS * KVDIM);
    float* biascat = (float*)(ws16 + o);

    split_x<<<2048, 256, 0, stream>>>(x, xh, xl, MROWS * HIDDEN / 4);
    split_wt<<<dim3(32, 32), 256, 0, stream>>>(Wq, HIDDEN, 0,    Wth, Wtl);
    split_wt<<<dim3(32, 8),  256, 0, stream>>>(Wk, KVDIM, 2048, Wth, Wtl);
    split_wt<<<dim3(32, 8),  256, 0, stream>>>(Wv, KVDIM, 2560, Wth, Wtl);
    biascat_k<<<12, 256, 0, stream>>>(bq, bk, bv, biascat);
    gemm_qkv<<<dim3(MROWS / 128, NQKV / 128), 256, 0, stream>>>(
        xh, xl, Wth, Wtl, biascat, qh, ql, khs, kls, vhs);
    attn7<<<dim3(32, 16), 256, 0, stream>>>(qh, ql, khs, kls, vhs, mask, (float*)d_out);
}

// Round 13
// 292.255 us; speedup vs baseline: 1.0650x; 1.0650x over previous
//
#include <hip/hip_runtime.h>
#include <math.h>

#define HIDDEN 2048
#define NHEADS 32
#define HDIM 64
#define GNUM 8
#define KVDIM 512
#define BB 2
#define SS 2048
#define MROWS (BB * SS)   // 4096
#define NQKV 3072

typedef _Float16 half8 __attribute__((ext_vector_type(8)));
typedef _Float16 half4 __attribute__((ext_vector_type(4)));
typedef _Float16 half2 __attribute__((ext_vector_type(2)));
typedef __fp16 fp16x2 __attribute__((ext_vector_type(2)));
typedef float floatx4 __attribute__((ext_vector_type(4)));

#define MFMA16(a, b, c) __builtin_amdgcn_mfma_f32_16x16x32_f16((a), (b), (c), 0, 0, 0)

// split x = hi + (lo/2048), lo scaled into fp16 normal range
__device__ __forceinline__ void split_f32(float x, _Float16& hi, _Float16& lo) {
    hi = (_Float16)x;
    lo = (_Float16)((x - (float)hi) * 2048.0f);
}

__device__ __forceinline__ void load_lds16(const void* g, void* l) {
    __builtin_amdgcn_global_load_lds(
        (const __attribute__((address_space(1))) void*)g,
        (__attribute__((address_space(3))) void*)l, 16, 0, 0);
}

// permlane swaps (gfx950): exchange 32-lane halves / odd-even 16-rows of two VGPRs
__device__ __forceinline__ void permswap32(unsigned& a, unsigned& b) {
    asm volatile("v_permlane32_swap_b32 %0, %1" : "+v"(a), "+v"(b));
}
__device__ __forceinline__ void permswap16(unsigned& a, unsigned& b) {
    asm volatile("v_permlane16_swap_b32 %0, %1" : "+v"(a), "+v"(b));
}

__device__ __forceinline__ unsigned pk_f16(float a, float b) {
    union { fp16x2 h; unsigned u; } c;
    c.h = __builtin_amdgcn_cvt_pkrtz(a, b);
    return c.u;
}

// ---------------------------------------------------------------------------
// x [4096][2048] f32 -> xh, xl fp16
// ---------------------------------------------------------------------------
__global__ __launch_bounds__(256)
void split_x(const float* __restrict__ x, _Float16* __restrict__ xh,
             _Float16* __restrict__ xl, int n4) {
    for (int idx = blockIdx.x * 256 + threadIdx.x; idx < n4; idx += gridDim.x * 256) {
        floatx4 v = reinterpret_cast<const floatx4*>(x)[idx];
        half4 h, l;
        #pragma unroll
        for (int e = 0; e < 4; ++e) { _Float16 hi, lo; split_f32(v[e], hi, lo); h[e] = hi; l[e] = lo; }
        reinterpret_cast<half4*>(xh)[idx] = h;
        reinterpret_cast<half4*>(xl)[idx] = l;
    }
}

// ---------------------------------------------------------------------------
// All three W's -> Wt rows of [NQKV][2048] fp16 hi/lo (transposed), ONE launch.
// grid (32, 48): nb<32 -> Wq (N=2048, n0=0); nb<40 -> Wk; else Wv.
// ---------------------------------------------------------------------------
__global__ __launch_bounds__(256)
void split_wt_all(const float* __restrict__ Wq, const float* __restrict__ Wk,
                  const float* __restrict__ Wv,
                  _Float16* __restrict__ Wth, _Float16* __restrict__ Wtl) {
    __shared__ float tile[64][68];
    const int tid = threadIdx.x;
    const int kb = blockIdx.x;
    int nb = blockIdx.y;
    const float* W; int N, n0;
    if (nb < 32)      { W = Wq; N = 2048; n0 = 0; }
    else if (nb < 40) { W = Wk; N = 512;  n0 = 2048; nb -= 32; }
    else              { W = Wv; N = 512;  n0 = 2560; nb -= 40; }

    #pragma unroll
    for (int i = 0; i < 4; ++i) {
        int idx = tid + i * 256;           // 64 rows x 16 float4
        int r = idx >> 4, c4 = idx & 15;
        floatx4 v = *reinterpret_cast<const floatx4*>(&W[(size_t)(kb * 64 + r) * N + nb * 64 + c4 * 4]);
        *reinterpret_cast<floatx4*>(&tile[r][c4 * 4]) = v;
    }
    __syncthreads();
    #pragma unroll
    for (int i = 0; i < 4; ++i) {
        int idx = tid + i * 256;
        int r2 = idx >> 4, c2 = (idx & 15) * 4;   // r2 = local n, c2 = local k
        half4 h, l;
        #pragma unroll
        for (int e = 0; e < 4; ++e) {
            _Float16 hi, lo;
            split_f32(tile[c2 + e][r2], hi, lo);
            h[e] = hi; l[e] = lo;
        }
        size_t o = (size_t)(n0 + nb * 64 + r2) * HIDDEN + kb * 64 + c2;
        *reinterpret_cast<half4*>(&Wth[o]) = h;
        *reinterpret_cast<half4*>(&Wtl[o]) = l;
    }
}

// ---------------------------------------------------------------------------
// Unified QKV GEMM (R10 structure): [4096][2048] @ [2048][3072] + bias,
// split-fp16 3-term; 128x128 tile, BK=64, 4 waves, 2 blocks/CU.
// K tiles [s][dim], V tiles [dim][s], both XOR-swizzled for attn DMA staging.
// V-only column blocks (bn>=20) use 1-term hi*hi (V stored fp16 anyway).
// Bias read directly from bq/bk/bv in the epilogue (no concat kernel).
// ---------------------------------------------------------------------------
__global__ __launch_bounds__(256, 2)
void gemm_qkv(const _Float16* __restrict__ xh, const _Float16* __restrict__ xl,
              const _Float16* __restrict__ Wth, const _Float16* __restrict__ Wtl,
              const float* __restrict__ bq, const float* __restrict__ bk,
              const float* __restrict__ bv,
              _Float16* __restrict__ qh, _Float16* __restrict__ ql,
              _Float16* __restrict__ khs, _Float16* __restrict__ kls,
              _Float16* __restrict__ vhs) {
    __shared__ __align__(16) _Float16 Ah[128 * 64];
    __shared__ __align__(16) _Float16 Al[128 * 64];
    __shared__ __align__(16) _Float16 Bh[128 * 64];
    __shared__ __align__(16) _Float16 Bl[128 * 64];

    const int tid  = threadIdx.x;
    const int lane = tid & 63;
    const int w    = tid >> 6;
    const int wm   = w >> 1, wn = w & 1;
    const int bm   = blockIdx.x, bn = blockIdx.y;
    const int ml   = lane & 15;
    const int kg8  = (lane >> 4) * 8;
    const bool lo3 = (bn < 20);   // Q/K blocks 3-term; V blocks (cols>=2560) 1-term

    const _Float16* gsrc;
    _Float16* ldst;
    if      (w == 0) { gsrc = xh  + (size_t)(bm * 128) * HIDDEN; ldst = Ah; }
    else if (w == 1) { gsrc = xl  + (size_t)(bm * 128) * HIDDEN; ldst = Al; }
    else if (w == 2) { gsrc = Wth + (size_t)(bn * 128) * HIDDEN; ldst = Bh; }
    else             { gsrc = Wtl + (size_t)(bn * 128) * HIDDEN; ldst = Bl; }
    const bool do_stage = lo3 || (w == 0) || (w == 2);

    floatx4 acc0[4][4] = {};
    floatx4 accL[4][4] = {};

    for (int k0 = 0; k0 < HIDDEN; k0 += 64) {
        if (do_stage) {
            #pragma unroll
            for (int i = 0; i < 16; ++i) {
                int L   = i * 1024 + lane * 16;            // linear LDS byte
                int row = L >> 7;                          // 128 B rows
                int off = (L & 127) ^ ((row & 7) << 4);    // inverse-swizzled src byte
                const void* gp = (const char*)(gsrc + (size_t)row * HIDDEN + k0) + off;
                void* lp = (char*)ldst + i * 1024;
                load_lds16(gp, lp);
            }
        }
        __syncthreads();

        #pragma unroll
        for (int kc = 0; kc < 2; ++kc) {
            half8 a_h[4], b_h[4];
            #pragma unroll
            for (int r = 0; r < 4; ++r) {
                int row = wm * 64 + r * 16 + ml;
                int byt = row * 128 + (((kc * 64 + kg8 * 2)) ^ ((row & 7) << 4));
                a_h[r] = *reinterpret_cast<const half8*>((const char*)Ah + byt);
            }
            #pragma unroll
            for (int c = 0; c < 4; ++c) {
                int row = wn * 64 + c * 16 + ml;
                int byt = row * 128 + (((kc * 64 + kg8 * 2)) ^ ((row & 7) << 4));
                b_h[c] = *reinterpret_cast<const half8*>((const char*)Bh + byt);
            }
            if (lo3) {
                half8 a_l[4], b_l[4];
                #pragma unroll
                for (int r = 0; r < 4; ++r) {
                    int row = wm * 64 + r * 16 + ml;
                    int byt = row * 128 + (((kc * 64 + kg8 * 2)) ^ ((row & 7) << 4));
                    a_l[r] = *reinterpret_cast<const half8*>((const char*)Al + byt);
                }
                #pragma unroll
                for (int c = 0; c < 4; ++c) {
                    int row = wn * 64 + c * 16 + ml;
                    int byt = row * 128 + (((kc * 64 + kg8 * 2)) ^ ((row & 7) << 4));
                    b_l[c] = *reinterpret_cast<const half8*>((const char*)Bl + byt);
                }
                #pragma unroll
                for (int r = 0; r < 4; ++r)
                    #pragma unroll
                    for (int c = 0; c < 4; ++c) {
                        acc0[r][c] = MFMA16(a_h[r], b_h[c], acc0[r][c]);
                        accL[r][c] = MFMA16(a_h[r], b_l[c], accL[r][c]);
                        accL[r][c] = MFMA16(a_l[r], b_h[c], accL[r][c]);
                    }
            } else {
                #pragma unroll
                for (int r = 0; r < 4; ++r)
                    #pragma unroll
                    for (int c = 0; c < 4; ++c)
                        acc0[r][c] = MFMA16(a_h[r], b_h[c], acc0[r][c]);
            }
        }
        __syncthreads();
    }

    // epilogue (bias read direct from bq/bk/bv)
    #pragma unroll
    for (int c = 0; c < 4; ++c) {
        int colg = bn * 128 + wn * 64 + c * 16 + ml;
        float bval = (colg < 2048) ? bq[colg]
                   : (colg < 2560) ? bk[colg - 2048]
                                   : bv[colg - 2560];
        #pragma unroll
        for (int r = 0; r < 4; ++r) {
            int rowg = bm * 128 + wm * 64 + r * 16 + (lane >> 4) * 4;
            #pragma unroll
            for (int reg = 0; reg < 4; ++reg) {
                float val = acc0[r][c][reg] + accL[r][c][reg] * (1.0f / 2048.0f) + bval;
                int rr = rowg + reg;
                if (colg < 2048) {
                    _Float16 hi, lo; split_f32(val, hi, lo);
                    qh[(size_t)rr * HIDDEN + colg] = hi;
                    ql[(size_t)rr * HIDDEN + colg] = lo;
                } else if (colg < 2560) {
                    // K: tiled [bg][kt][s(64)][d(64)], col d swizzled by s&7
                    int ck = colg - 2048;
                    int gk = ck >> 6, dk = ck & 63;
                    int bk_ = rr >> 11, sk_ = rr & 2047;
                    int kk = sk_ & 63;
                    size_t baseK = ((size_t)((bk_ * 8 + gk) * 32 + (sk_ >> 6))) * 4096
                                 + kk * 64 + (dk ^ ((kk & 7) << 3));
                    _Float16 hi, lo; split_f32(val, hi, lo);
                    khs[baseK] = hi;
                    kls[baseK] = lo;
                } else {
                    // V: tiled TRANSPOSED [bg][kt][d(64)][s(64)], col s swizzled by d&7
                    int ck = colg - 2560;
                    int gk = ck >> 6, dk = ck & 63;
                    int bk_ = rr >> 11, sk_ = rr & 2047;
                    int s6 = sk_ & 63;
                    size_t baseV = ((size_t)((bk_ * 8 + gk) * 32 + (sk_ >> 6))) * 4096
                                 + dk * 64 + (s6 ^ ((dk & 7) << 3));
                    vhs[baseV] = (_Float16)val;
                }
            }
        }
    }
}

// ---------------------------------------------------------------------------
// Fused attention (R10-proven attn7), in-register scores; K AND V staged via
// global_load_lds DMA from pre-swizzled tiled layouts (w0:K_hi w1:K_lo w2:V^T).
//   S^T = mfma(K,Q); floor/mask in regs; permlane32+16 swap -> SV B-frags;
//   out^T = mfma(V^T, S^T).  Block = (b, g, 64 q-rows), 4 heads share K/V.
// ---------------------------------------------------------------------------
__global__ __launch_bounds__(256, 2)
void attn7(const _Float16* __restrict__ qh, const _Float16* __restrict__ ql,
           const _Float16* __restrict__ khs, const _Float16* __restrict__ kls,
           const _Float16* __restrict__ vhs, const int* __restrict__ mask,
           float* __restrict__ out) {
    __shared__ __align__(16) _Float16 Ksh[64 * 64];   // linear, XOR-swizzled content
    __shared__ __align__(16) _Float16 Ksl[64 * 64];
    __shared__ __align__(16) _Float16 Vs[64 * 64];    // [dim][s], swizzled content

    const int tid  = threadIdx.x;
    const int lane = tid & 63;
    const int w    = tid >> 6;
    const int ml   = lane & 15;
    const int lg   = lane >> 4;
    const int kg8  = lg * 8;

    // XCD-aware remap: all 32 q-tiles of one (b,g) on the same XCD
    const int f_  = blockIdx.y * 32 + blockIdx.x;      // 0..511
    const int bg  = (f_ & 7) | ((f_ >> 8) << 3);
    const int qt  = (f_ >> 3) & 31;
    const int b   = bg >> 3, g = bg & 7;

    // hoist Q fragments (16 rows this wave, 4 heads), pre-scaled by 1/8 (exact)
    half8 qhf[4][2], qlf[4][2];
    {
        size_t rowbase = (size_t)(b * SS + qt * 64 + w * 16 + ml) * HIDDEN;
        #pragma unroll
        for (int hh = 0; hh < 4; ++hh) {
            int hcol = (g * 4 + hh) * HDIM;
            #pragma unroll
            for (int gch = 0; gch < 2; ++gch) {
                half8 a = *reinterpret_cast<const half8*>(&qh[rowbase + hcol + gch * 32 + kg8]);
                half8 c = *reinterpret_cast<const half8*>(&ql[rowbase + hcol + gch * 32 + kg8]);
                qhf[hh][gch] = a * (_Float16)0.125f;
                qlf[hh][gch] = c * (_Float16)0.125f;
            }
        }
    }

    const _Float16* ktile_h = khs + (size_t)(bg * 32) * 4096;
    const _Float16* ktile_l = kls + (size_t)(bg * 32) * 4096;
    const _Float16* vtile   = vhs + (size_t)(bg * 32) * 4096;
    const int* mb = mask + b * SS;

    floatx4 oacc[4][4] = {};   // [head][dim-frag]; col=q, row=d

    for (int kt = 0; kt < SS / 64; ++kt) {
        __syncthreads();   // previous tile fully consumed
        if (w == 0) {
            #pragma unroll
            for (int j = 0; j < 8; ++j)
                load_lds16((const char*)(ktile_h + (size_t)kt * 4096) + j * 1024 + lane * 16,
                           (char*)Ksh + j * 1024);
        } else if (w == 1) {
            #pragma unroll
            for (int j = 0; j < 8; ++j)
                load_lds16((const char*)(ktile_l + (size_t)kt * 4096) + j * 1024 + lane * 16,
                           (char*)Ksl + j * 1024);
        } else if (w == 2) {
            #pragma unroll
            for (int j = 0; j < 8; ++j)
                load_lds16((const char*)(vtile + (size_t)kt * 4096) + j * 1024 + lane * 16,
                           (char*)Vs + j * 1024);
        }
        __syncthreads();

        // hoist V^T fragments (shared across heads); same swizzled pattern as K
        half8 av[4][2];
        #pragma unroll
        for (int f = 0; f < 4; ++f) {
            int vrow = f * 16 + ml;
            int vxo = (vrow & 7) << 3;
            #pragma unroll
            for (int kc = 0; kc < 2; ++kc)
                av[f][kc] = *reinterpret_cast<const half8*>(
                    &Vs[vrow * 64 + ((kc * 32 + kg8) ^ vxo)]);
        }

        int4 m4v[4];
        #pragma unroll
        for (int fc = 0; fc < 4; ++fc)
            m4v[fc] = *reinterpret_cast<const int4*>(&mb[kt * 64 + fc * 16 + lg * 4]);

        __builtin_amdgcn_s_setprio(1);

        // QK^T (swapped): per fc read K-frags once, all 4 heads consume
        unsigned h2[4][4][2];   // [hh][fc][p] packed fp16 score pairs
        #pragma unroll
        for (int fc = 0; fc < 4; ++fc) {
            int krow = fc * 16 + ml;
            int xo = (krow & 7) << 3;
            half8 k_h[2], k_l[2];
            #pragma unroll
            for (int gch = 0; gch < 2; ++gch) {
                k_h[gch] = *reinterpret_cast<const half8*>(&Ksh[krow * 64 + ((gch * 32 + kg8) ^ xo)]);
                k_l[gch] = *reinterpret_cast<const half8*>(&Ksl[krow * 64 + ((gch * 32 + kg8) ^ xo)]);
            }
            #pragma unroll
            for (int hh = 0; hh < 4; ++hh) {
                floatx4 s0 = {}, sl = {};
                s0 = MFMA16(k_h[0], qhf[hh][0], s0);
                s0 = MFMA16(k_h[1], qhf[hh][1], s0);
                sl = MFMA16(k_l[0], qhf[hh][0], sl);
                sl = MFMA16(k_l[1], qhf[hh][1], sl);
                sl = MFMA16(k_h[0], qlf[hh][0], sl);
                sl = MFMA16(k_h[1], qlf[hh][1], sl);
                float sv[4];
                #pragma unroll
                for (int r = 0; r < 4; ++r) {
                    float t = floorf(fmaf(sl[r], 1.0f / 2048.0f, s0[r]));
                    sv[r] = (m4v[fc][r] == 0) ? -INFINITY : t;
                }
                h2[hh][fc][0] = pk_f16(sv[0], sv[1]);
                h2[hh][fc][1] = pk_f16(sv[2], sv[3]);
            }
        }

        // S @ V via out^T = mfma(V^T-frag, S^T-B-frag built by permlane swaps)
        #pragma unroll
        for (int hh = 0; hh < 4; ++hh) {
            #pragma unroll
            for (int kc = 0; kc < 2; ++kc) {
                unsigned t0 = h2[hh][2 * kc][0], tA = h2[hh][2 * kc + 1][0];
                unsigned t1 = h2[hh][2 * kc][1], tB = h2[hh][2 * kc + 1][1];
                permswap32(t0, tA); permswap16(t0, tA);
                permswap32(t1, tB); permswap16(t1, tB);
                union { unsigned u[4]; half8 h; } bu;
                bu.u[0] = t0; bu.u[1] = t1; bu.u[2] = tA; bu.u[3] = tB;
                #pragma unroll
                for (int f = 0; f < 4; ++f)
                    oacc[hh][f] = MFMA16(av[f][kc], bu.h, oacc[hh][f]);
            }
        }
        __builtin_amdgcn_s_setprio(0);
    }

    // epilogue: out^T layout -> float4 stores (4 consecutive dims per store)
    #pragma unroll
    for (int hh = 0; hh < 4; ++hh) {
        int hcol = (g * 4 + hh) * HDIM;
        #pragma unroll
        for (int f = 0; f < 4; ++f) {
            size_t row = (size_t)(b * SS + qt * 64 + w * 16 + ml);
            *reinterpret_cast<floatx4*>(&out[row * HIDDEN + hcol + f * 16 + lg * 4]) = oacc[hh][f];
        }
    }
}

extern "C" void kernel_launch(void* const* d_in, const int* in_sizes, int n_in,
                              void* d_out, int out_size, void* d_ws, size_t ws_size,
                              hipStream_t stream) {
    (void)in_sizes; (void)n_in; (void)out_size; (void)ws_size;
    const float* x    = (const float*)d_in[0];
    const int*   mask = (const int*)d_in[1];
    const float* Wq   = (const float*)d_in[2];
    const float* bq   = (const float*)d_in[3];
    const float* Wk   = (const float*)d_in[4];
    const float* bk   = (const float*)d_in[5];
    const float* Wv   = (const float*)d_in[6];
    const float* bv   = (const float*)d_in[7];

    _Float16* ws16 = (_Float16*)d_ws;
    size_t o = 0;
    auto alloc16 = [&](size_t n) { _Float16* p = ws16 + o; o += n; return p; };
    _Float16* xh  = alloc16((size_t)MROWS * HIDDEN);
    _Float16* xl  = alloc16((size_t)MROWS * HIDDEN);
    _Float16* Wth = alloc16((size_t)NQKV * HIDDEN);
    _Float16* Wtl = alloc16((size_t)NQKV * HIDDEN);
    _Float16* qh  = alloc16((size_t)MROWS * HIDDEN);
    _Float16* ql  = alloc16((size_t)MROWS * HIDDEN);
    _Float16* khs = alloc16((size_t)MROWS * KVDIM);
    _Float16* kls = alloc16((size_t)MROWS * KVDIM);
    _Float16* vhs = alloc16((size_t)MROWS * KVDIM);

    split_x<<<2048, 256, 0, stream>>>(x, xh, xl, MROWS * HIDDEN / 4);
    split_wt_all<<<dim3(32, 48), 256, 0, stream>>>(Wq, Wk, Wv, Wth, Wtl);
    gemm_qkv<<<dim3(MROWS / 128, NQKV / 128), 256, 0, stream>>>(
        xh, xl, Wth, Wtl, bq, bk, bv, qh, ql, khs, kls, vhs);
    attn7<<<dim3(32, 16), 256, 0, stream>>>(qh, ql, khs, kls, vhs, mask, (float*)d_out);
}